// Round 5
// baseline (555.215 us; speedup 1.0000x reference)
//
#include <hip/hip_runtime.h>
#include <hip/hip_bf16.h>

// 2-layer 4-direction MDLSTM, fused, one dispatch. B=256, Wd=2048, OUT=11.
// R12: TWO CHAINS PER WAVE. 64 lanes = 2 halves x (16 units x 2 lanes);
// each half runs an independent chunk-chain of the same direction
// (half1 = ck+4). Each lane computes 2 gate dots (gc0:{i,o}, gc1:{f,a})
// via 12 fdot2 -- per-chain fdot2 unchanged, but trans ops, distribution,
// cell update and loop overhead are HALVED per chain (R11 showed ~176
// issue-cyc/wave-step, mostly per-wave-step costs). Distribution via
// 6x ds_bpermute (full-wave crossbar, per-half sources, DS pipe, addrs
// precomputed). Act exchange via one quad_perm dpp per act. 32 chains =
// 4 dirs x 8 chunks of 256 + UNIFORM 64-step warm (ck0 runs a wrapped
// garbage warm; its state re-zeroed at the main-loop boundary -> fully
// uniform control flow, compile-time loop counts). Dummy units j>=11:
// scl=0 => hj == 0 exactly (old unit-11 algebra); writes masked gc0&&j<=10.
// Carries R11: single-chain 6-dot accum, 2x unroll. R8: hj=fma(2o,rcp,-o).
// R7: fdot2 packed dots, f16-pair y strip, exp2-folded activations.
// NO readlane distribution anymore; no LDS h-buffer (bpermute is memoryless).

#define NOUT 11
#define WD 2048
#define NB 256
#define ROW 12
#define ACCN (WD * ROW)
#define YROW 6
#define YPAD 12
#define YBFN (WD * YROW + 2 * YPAD)

#define NTHR 1024
#define NCK 8       // chunks per direction
#define CHUNK 256   // WD / NCK
#define WARM 64     // uniform warm-up steps (ck0 wrapped+rezeroed); even

typedef float f2 __attribute__((ext_vector_type(2)));
typedef float f4 __attribute__((ext_vector_type(4)));
typedef unsigned int u32;
typedef u32 u32x2 __attribute__((ext_vector_type(2)));
typedef __fp16 h2 __attribute__((ext_vector_type(2)));

#define LOG2E 1.4426950408889634f

union UH { u32 u; h2 h; };
__device__ __forceinline__ u32 h2u(h2 v) { UH x; x.h = v; return x.u; }
__device__ __forceinline__ h2 u2h(u32 v) { UH x; x.u = v; return x.h; }

template <int CTRL>
__device__ __forceinline__ float dppf(float v) {
  return __int_as_float(__builtin_amdgcn_update_dpp(
      __float_as_int(v), __float_as_int(v), CTRL, 0xF, 0xF, false));
}
__device__ __forceinline__ float rcp_(float x) { return __builtin_amdgcn_rcpf(x); }
__device__ __forceinline__ float exp2_(float x) { return __builtin_amdgcn_exp2f(x); }
__device__ __forceinline__ float dot2(h2 a, h2 b, float c) {
  return __builtin_amdgcn_fdot2(a, b, c, false);
}
__device__ __forceinline__ h2 bperm(int addr, h2 src) {
  return u2h((u32)__builtin_amdgcn_ds_bpermute(addr, (int)h2u(src)));
}

// DOACC: compile-time 0/1 (warm-up steps don't accumulate).
// In scope: hj, cpr, giA, giB, ao, ad, UpA[6], UpB[6], kABv, kBBv, wr,
// bpa0..bpa5, acc. __VA_ARGS__ = off-chain PREP (sets gnA, gnB).
#define STEP(DOACC, ...)                                                       \
  do {                                                                         \
    const float hsh = dppf<0x102>(hj); /* row_shl:2: lane i <- lane i+2 */     \
    const h2 hpk = __builtin_amdgcn_cvt_pkrtz(hj, hsh);                        \
    const h2 hp0 = bperm(bpa0, hpk); /* pair k from own half's lane 4k */      \
    const h2 hp1 = bperm(bpa1, hpk);                                           \
    const h2 hp2 = bperm(bpa2, hpk);                                           \
    const h2 hp3 = bperm(bpa3, hpk);                                           \
    const h2 hp4 = bperm(bpa4, hpk);                                           \
    const h2 hp5 = bperm(bpa5, hpk);                                           \
    __VA_ARGS__                                                                \
    float gA = dot2(hp0, UpA[0], giA);                                         \
    gA = dot2(hp1, UpA[1], gA);                                                \
    gA = dot2(hp2, UpA[2], gA);                                                \
    gA = dot2(hp3, UpA[3], gA);                                                \
    gA = dot2(hp4, UpA[4], gA);                                                \
    gA = dot2(hp5, UpA[5], gA);                                                \
    float gB = dot2(hp0, UpB[0], giB);                                         \
    gB = dot2(hp1, UpB[1], gB);                                                \
    gB = dot2(hp2, UpB[2], gB);                                                \
    gB = dot2(hp3, UpB[3], gB);                                                \
    gB = dot2(hp4, UpB[4], gB);                                                \
    gB = dot2(hp5, UpB[5], gB);                                                \
    const float sA = rcp_(1.0f + exp2_(gA)); /* actA: i (gc0) / f (gc1) */     \
    const float sB = rcp_(1.0f + exp2_(gB));                                   \
    const float actB = fmaf(kABv, sB, kBBv); /* o (gc0) / a-scaled (gc1) */    \
    const float swA = dppf<0xB1>(sA);    /* quad_perm[1,0,3,2]: f on gc0 */    \
    const float swB = dppf<0xB1>(actB);  /* a on gc0 */                        \
    const float ov2 = actB + actB; /* off-chain */                             \
    cpr = fmaf(swA, cpr, sA * swB); /* gc0: f*c + i*a (pre-scaled) */          \
    const float r2t = rcp_(1.0f + exp2_(cpr));                                 \
    hj = fmaf(ov2, r2t, -actB); /* gc0: o*(2*r2t-1) */                         \
    if (DOACC && wr) atomicAdd(&acc[ao], hj);                                  \
    ao += ad;                                                                  \
  } while (0)

__global__ __launch_bounds__(NTHR, 1) void mdlstm_fused(
    const float* __restrict__ x, const float* __restrict__ W0,
    const float* __restrict__ U0, const float* __restrict__ b0,
    const float* __restrict__ W1, const float* __restrict__ U1,
    const float* __restrict__ b1, float* __restrict__ out) {
  __shared__ __align__(16) float acc[ACCN];  // 96 KB
  __shared__ __align__(16) u32 ybf[YBFN];    // 48.1 KB (xw f32 | y f16-pairs)

  const int tid = threadIdx.x;
  const int b = blockIdx.x;
  float* xw = (float*)ybf;

  // ---- Phase A: height-sum x -> xw; zero acc ----
  {
    const f4* xb4 = (const f4*)(x + (size_t)b * 32 * WD);
    f4* xw4 = (f4*)xw;
    for (int w = tid; w < WD / 4; w += NTHR) {
      f4 s = xb4[w];
#pragma unroll
      for (int h = 1; h < 32; ++h) s += xb4[h * (WD / 4) + w];
      xw4[w] = s;
    }
    f4* a4 = (f4*)acc;
    const f4 z = {0.f, 0.f, 0.f, 0.f};
    for (int i = tid; i < ACCN / 4; i += NTHR) a4[i] = z;
  }
  __syncthreads();

  const int lane = tid & 63;
  const int wv = tid >> 6;
  const int half = lane >> 5;                // 0/1: which chain in the wave
  const int d = wv & 3;                      // direction (wave-uniform)
  const int ck = (wv >> 2) + (half << 2);    // chunk 0..7 (per half)
  const bool fwd = ((d & 1) == 0);
  const int base = ck * CHUNK;
  const int j = (lane & 31) >> 1;            // unit 0..15 (11..15 dummy)
  const int gc = lane & 1;                   // 0:{i,o} 1:{f,a}
  const bool real = (j <= 10);
  const bool wr = (gc == 0) && real;
  const bool ck0z = (ck == 0);               // re-zero after wrapped warm
  // gate columns: i:0-10 f:11-21 o:33-43 a:44-54; dummy -> col 54, scl 0
  const int colA = real ? ((gc == 0) ? j : 11 + j) : 54;
  const int colB = real ? ((gc == 0) ? 33 + j : 44 + j) : 54;
  const float sclA = real ? -LOG2E : 0.f;
  const float sclB = real ? ((gc == 0) ? -LOG2E : -2.f * LOG2E) : 0.f;
  const float kABv = (gc == 0) ? 1.f : (-4.f * LOG2E);
  const float kBBv = (gc == 0) ? 0.f : (2.f * LOG2E);
  // bpermute byte addrs: pair k lives at lane (half*32 + 4k)
  const int bpa0 = ((lane & 32) << 2);
  const int bpa1 = bpa0 + 16;
  const int bpa2 = bpa0 + 32;
  const int bpa3 = bpa0 + 48;
  const int bpa4 = bpa0 + 64;
  const int bpa5 = bpa0 + 80;

  const int p0 = fwd ? (base - WARM) : (WD - 1 - base + WARM);
  const int xd = fwd ? 1 : -1;
  const int ad = fwd ? ROW : -ROW;
  const int qd = fwd ? 3 : -3;

  // ---- Phase B: layer-1 scan ----
  {
    float uvA[12], uvB[12];
#pragma unroll
    for (int s = 0; s < NOUT; ++s) {
      uvA[s] = U0[(d * NOUT + s) * 55 + colA] * sclA;
      uvB[s] = U0[(d * NOUT + s) * 55 + colB] * sclB;
    }
    uvA[11] = 0.f;
    uvB[11] = 0.f;
    h2 UpA[6], UpB[6];
#pragma unroll
    for (int k = 0; k < 6; ++k) {
      UpA[k] = __builtin_amdgcn_cvt_pkrtz(uvA[2 * k], uvA[2 * k + 1]);
      UpB[k] = __builtin_amdgcn_cvt_pkrtz(uvB[2 * k], uvB[2 * k + 1]);
    }
    const float WcsA = W0[d * 55 + colA] * sclA;
    const float bcsA = b0[d * 55 + colA] * sclA;
    const float WcsB = W0[d * 55 + colB] * sclB;
    const float bcsB = b0[d * 55 + colB] * sclB;

    int xo = p0;               // per-lane (halves differ); & wraps ck0 warm
    int ao = p0 * ROW + j;     // no wrap needed: warm never writes
    float hj = 0.f, cpr = 0.f, gnA = 0.f, gnB = 0.f;
    const float xc = xw[xo & (WD - 1)];
    xo += xd;
    float giA = fmaf(xc, WcsA, bcsA);
    float giB = fmaf(xc, WcsB, bcsB);
    float xn = xw[xo & (WD - 1)];
    xo += xd;

#define PREP1                                                                  \
    const float xn2 = xw[xo & (WD - 1)]; /* prefetch t+2 (off-chain) */        \
    xo += xd;                                                                  \
    gnA = fmaf(xn, WcsA, bcsA);          /* input stage t+1 */                 \
    gnB = fmaf(xn, WcsB, bcsB);                                                \
    xn = xn2;

    for (int t = 0; t < WARM; t += 2) {
      STEP(0, PREP1);
      giA = gnA; giB = gnB;
      STEP(0, PREP1);
      giA = gnA; giB = gnB;
    }
    // ck0 ran a wrapped garbage warm purely for uniform control flow;
    // its true initial state is exactly zero. gi pipeline holds REAL
    // inputs for positions base, base+1 (last warm reads are in-range).
    hj = ck0z ? 0.f : hj;
    cpr = ck0z ? 0.f : cpr;
    for (int t = 0; t < CHUNK; t += 2) {
      STEP(1, PREP1);
      giA = gnA; giB = gnB;
      STEP(1, PREP1);
      giA = gnA; giB = gnB;
    }
#undef PREP1
  }
  __syncthreads();

  // ---- Phase C: pack acc -> f16-pair ybf (+ zero pads); re-zero acc ----
  {
    const f2* a2 = (const f2*)acc;
    for (int i = tid; i < WD * YROW; i += NTHR) {
      const f2 v = a2[i];
      ybf[YPAD + i] = h2u(__builtin_amdgcn_cvt_pkrtz(v.x, v.y));
    }
    if (tid < YPAD) {
      ybf[tid] = 0;
      ybf[WD * YROW + YPAD + tid] = 0;
    }
  }
  __syncthreads();
  {
    f4* a4 = (f4*)acc;
    const f4 z = {0.f, 0.f, 0.f, 0.f};
    for (int i = tid; i < ACCN / 4; i += NTHR) a4[i] = z;
  }
  __syncthreads();

  // ---- Phase D: layer-2 scan ----
  {
    float uvA[12], uvB[12], wvA[12], wvB[12];
#pragma unroll
    for (int s = 0; s < NOUT; ++s) {
      uvA[s] = U1[(d * NOUT + s) * 55 + colA] * sclA;
      uvB[s] = U1[(d * NOUT + s) * 55 + colB] * sclB;
      wvA[s] = W1[(d * NOUT + s) * 55 + colA] * sclA;
      wvB[s] = W1[(d * NOUT + s) * 55 + colB] * sclB;
    }
    uvA[11] = uvB[11] = wvA[11] = wvB[11] = 0.f;
    h2 UpA[6], UpB[6], WpA[6], WpB[6];
#pragma unroll
    for (int k = 0; k < 6; ++k) {
      UpA[k] = __builtin_amdgcn_cvt_pkrtz(uvA[2 * k], uvA[2 * k + 1]);
      UpB[k] = __builtin_amdgcn_cvt_pkrtz(uvB[2 * k], uvB[2 * k + 1]);
      WpA[k] = __builtin_amdgcn_cvt_pkrtz(wvA[2 * k], wvA[2 * k + 1]);
      WpB[k] = __builtin_amdgcn_cvt_pkrtz(wvB[2 * k], wvB[2 * k + 1]);
    }
    const float bcsA = b1[d * 55 + colA] * sclA;
    const float bcsB = b1[d * 55 + colB] * sclB;

    const u32x2* yv = (const u32x2*)ybf;  // row r -> yv[3r+6 .. 3r+8]
    int q = 3 * p0 + 6;                   // per-lane; ck0 warm reads garbage
                                          // (in-LDS, harmless, state rezeroed)

    auto GIA = [&](u32x2 r0, u32x2 r1, u32x2 r2) -> float {
      float A = dot2(u2h(r0.x), WpA[0], bcsA);
      A = dot2(u2h(r0.y), WpA[1], A);
      A = dot2(u2h(r1.x), WpA[2], A);
      A = dot2(u2h(r1.y), WpA[3], A);
      A = dot2(u2h(r2.x), WpA[4], A);
      A = dot2(u2h(r2.y), WpA[5], A);
      return A;
    };
    auto GIB = [&](u32x2 r0, u32x2 r1, u32x2 r2) -> float {
      float A = dot2(u2h(r0.x), WpB[0], bcsB);
      A = dot2(u2h(r0.y), WpB[1], A);
      A = dot2(u2h(r1.x), WpB[2], A);
      A = dot2(u2h(r1.y), WpB[3], A);
      A = dot2(u2h(r2.x), WpB[4], A);
      A = dot2(u2h(r2.y), WpB[5], A);
      return A;
    };

    u32x2 c0 = yv[q];
    u32x2 c1 = yv[q + 1];
    u32x2 c2 = yv[q + 2];
    q += qd;
    u32x2 pr0 = yv[q];
    u32x2 pr1 = yv[q + 1];
    u32x2 pr2 = yv[q + 2];
    q += qd;

    float giA = GIA(c0, c1, c2);
    float giB = GIB(c0, c1, c2);

    int ao = p0 * ROW + j;
    float hj = 0.f, cpr = 0.f, gnA = 0.f, gnB = 0.f;

#define PREP2                                                                  \
    const u32x2 n0 = yv[q];          /* prefetch row t+2 (off-chain) */        \
    const u32x2 n1 = yv[q + 1];                                                \
    const u32x2 n2 = yv[q + 2];                                                \
    q += qd;                                                                   \
    gnA = GIA(pr0, pr1, pr2);        /* input stage t+1 */                     \
    gnB = GIB(pr0, pr1, pr2);                                                  \
    pr0 = n0;                                                                  \
    pr1 = n1;                                                                  \
    pr2 = n2;

    for (int t = 0; t < WARM; t += 2) {
      STEP(0, PREP2);
      giA = gnA; giB = gnB;
      STEP(0, PREP2);
      giA = gnA; giB = gnB;
    }
    hj = ck0z ? 0.f : hj;
    cpr = ck0z ? 0.f : cpr;
    for (int t = 0; t < CHUNK; t += 2) {
      STEP(1, PREP2);
      giA = gnA; giB = gnB;
      STEP(1, PREP2);
      giA = gnA; giB = gnB;
    }
#undef PREP2
  }
  __syncthreads();

  // ---- Phase E: writeout out[b][j][w] = acc[w*ROW+j] ----
  float* ob = out + (size_t)b * (NOUT * WD);
  for (int i = tid; i < NOUT * WD; i += NTHR) {
    const int jj = i >> 11;
    const int w = i & (WD - 1);
    ob[i] = acc[w * ROW + jj];
  }
}

extern "C" void kernel_launch(void* const* d_in, const int* in_sizes, int n_in,
                              void* d_out, int out_size, void* d_ws,
                              size_t ws_size, hipStream_t stream) {
  const float* x  = (const float*)d_in[0];
  const float* W0 = (const float*)d_in[1];
  const float* U0 = (const float*)d_in[2];
  const float* b0 = (const float*)d_in[3];
  const float* W1 = (const float*)d_in[4];
  const float* U1 = (const float*)d_in[5];
  const float* b1 = (const float*)d_in[6];
  float* out = (float*)d_out;

  mdlstm_fused<<<NB, NTHR, 0, stream>>>(x, W0, U0, b0, W1, U1, b1, out);
}

// Round 6
// 477.429 us; speedup vs baseline: 1.1629x; 1.1629x over previous
//
#include <hip/hip_runtime.h>
#include <hip/hip_bf16.h>

// 2-layer 4-direction MDLSTM, fused, one dispatch. B=256, Wd=2048, OUT=11.
// R13: UNIT-PER-LANE, 4 CHAINS PER WAVE. 16-lane group = one chain; lane u
// of a group owns unit u (u=11..15 dummy, zero weights => h == 0 exactly).
// Each lane computes all 4 gates of its unit (24 fdot2), its own cell and
// tanh -- trans ops drop to 2.5/chain (vs 10), act dpp-broadcasts vanish.
// h-distribution: pack pairs via dpp row_shl:1 + cvt_pkrtz, then 6x
// ds_swizzle (BitMode new=(old&0x10)|2k: per-group broadcast within
// 32-lane halves; memoryless crossbar, no LDS RAM race). DS budget
// ~10 ops/wave-step x 8 waves/CU ~ 55% of pipe (R12's bpermute design
// oversubscribed DS 1.5-2x at 16 waves -- the 504us regression).
// 512 thr = 8 waves = 32 chains = 4 dirs x 8 chunks (CHUNK 256), uniform
// WARM=64 (ck0 wrapped garbage warm + state rezero; proven R12). Per-chain
// math bit-identical to R11 (f32 fdot2 gates, f32 cell).
// Carries R11: single-chain 6-dot accum, 2x unroll. R8: hj=fma(2o,rcp,-o).
// R7: fdot2 packed dots, f16-pair y strip, exp2-folded activations.

#define NOUT 11
#define WD 2048
#define NB 256
#define ROW 12
#define ACCN (WD * ROW)
#define YROW 6
#define YPAD 12
#define YBFN (WD * YROW + 2 * YPAD)

#define NTHR 512
#define NCK 8       // chunks per direction
#define CHUNK 256   // WD / NCK
#define WARM 64     // uniform warm (ck0 wrapped+rezeroed); even

typedef float f2 __attribute__((ext_vector_type(2)));
typedef float f4 __attribute__((ext_vector_type(4)));
typedef unsigned int u32;
typedef u32 u32x2 __attribute__((ext_vector_type(2)));
typedef __fp16 h2 __attribute__((ext_vector_type(2)));

#define LOG2E 1.4426950408889634f

union UH { u32 u; h2 h; };
__device__ __forceinline__ u32 h2u(h2 v) { UH x; x.h = v; return x.u; }
__device__ __forceinline__ h2 u2h(u32 v) { UH x; x.u = v; return x.h; }

template <int CTRL>
__device__ __forceinline__ float dppf(float v) {
  return __int_as_float(__builtin_amdgcn_update_dpp(
      __float_as_int(v), __float_as_int(v), CTRL, 0xF, 0xF, false));
}
// BitMode swizzle: new_lane = ((lane & and) | or) ^ xor, within 32-lane
// halves (bit5 preserved). IMM = (xor<<10)|(or<<5)|and.
template <int IMM>
__device__ __forceinline__ h2 swzh(h2 v) {
  return u2h((u32)__builtin_amdgcn_ds_swizzle((int)h2u(v), IMM));
}
__device__ __forceinline__ float rcp_(float x) { return __builtin_amdgcn_rcpf(x); }
__device__ __forceinline__ float exp2_(float x) { return __builtin_amdgcn_exp2f(x); }
__device__ __forceinline__ float dot2(h2 a, h2 b, float c) {
  return __builtin_amdgcn_fdot2(a, b, c, false);
}

// DOACC: compile-time 0/1 (warm-up steps don't accumulate).
// In scope: hj, cpr, giI/F/O/A, ao, ad, UpI/F/O/A[6], wr, acc.
// __VA_ARGS__ = off-chain PREP (sets gnI/F/O/A); placed between the
// swizzles and the dependent dots to cover swizzle latency.
#define STEP(DOACC, ...)                                                       \
  do {                                                                         \
    const float hnx = dppf<0x101>(hj); /* row_shl:1 (within 16-lane group) */  \
    const h2 hpk = __builtin_amdgcn_cvt_pkrtz(hj, hnx); /* lane 2k: pack k */  \
    const h2 hp0 = swzh<0x010>(hpk); /* (grp&1)*16 + 0  */                     \
    const h2 hp1 = swzh<0x050>(hpk); /* + 2 */                                 \
    const h2 hp2 = swzh<0x090>(hpk); /* + 4 */                                 \
    const h2 hp3 = swzh<0x0D0>(hpk); /* + 6 */                                 \
    const h2 hp4 = swzh<0x110>(hpk); /* + 8 */                                 \
    const h2 hp5 = swzh<0x150>(hpk); /* + 10 */                                \
    __VA_ARGS__                                                                \
    float gI = dot2(hp0, UpI[0], giI);                                         \
    gI = dot2(hp1, UpI[1], gI);                                                \
    gI = dot2(hp2, UpI[2], gI);                                                \
    gI = dot2(hp3, UpI[3], gI);                                                \
    gI = dot2(hp4, UpI[4], gI);                                                \
    gI = dot2(hp5, UpI[5], gI);                                                \
    float gF = dot2(hp0, UpF[0], giF);                                         \
    gF = dot2(hp1, UpF[1], gF);                                                \
    gF = dot2(hp2, UpF[2], gF);                                                \
    gF = dot2(hp3, UpF[3], gF);                                                \
    gF = dot2(hp4, UpF[4], gF);                                                \
    gF = dot2(hp5, UpF[5], gF);                                                \
    float gO = dot2(hp0, UpO[0], giO);                                         \
    gO = dot2(hp1, UpO[1], gO);                                                \
    gO = dot2(hp2, UpO[2], gO);                                                \
    gO = dot2(hp3, UpO[3], gO);                                                \
    gO = dot2(hp4, UpO[4], gO);                                                \
    gO = dot2(hp5, UpO[5], gO);                                                \
    float gA = dot2(hp0, UpA[0], giA);                                         \
    gA = dot2(hp1, UpA[1], gA);                                                \
    gA = dot2(hp2, UpA[2], gA);                                                \
    gA = dot2(hp3, UpA[3], gA);                                                \
    gA = dot2(hp4, UpA[4], gA);                                                \
    gA = dot2(hp5, UpA[5], gA);                                                \
    const float sI = rcp_(1.0f + exp2_(gI));                                   \
    const float sF = rcp_(1.0f + exp2_(gF));                                   \
    const float sO = rcp_(1.0f + exp2_(gO));                                   \
    const float sA = rcp_(1.0f + exp2_(gA));                                   \
    const float taS = fmaf(-4.0f * LOG2E, sA, 2.0f * LOG2E); /* -2L*tanh */    \
    cpr = fmaf(sF, cpr, sI * taS); /* cpr == -2*log2e*c */                     \
    const float r2t = rcp_(1.0f + exp2_(cpr)); /* sigma(2c) */                 \
    const float sO2 = sO + sO;                                                 \
    hj = fmaf(sO2, r2t, -sO); /* o * tanh(c) */                                \
    if (DOACC && wr) atomicAdd(&acc[ao], hj);                                  \
    ao += ad;                                                                  \
  } while (0)

__global__ __launch_bounds__(NTHR, 1) void mdlstm_fused(
    const float* __restrict__ x, const float* __restrict__ W0,
    const float* __restrict__ U0, const float* __restrict__ b0,
    const float* __restrict__ W1, const float* __restrict__ U1,
    const float* __restrict__ b1, float* __restrict__ out) {
  __shared__ __align__(16) float acc[ACCN];  // 96 KB
  __shared__ __align__(16) u32 ybf[YBFN];    // 48.1 KB (xw f32 | y f16-pairs)

  const int tid = threadIdx.x;
  const int b = blockIdx.x;
  float* xw = (float*)ybf;

  // ---- Phase A: height-sum x -> xw; zero acc ----
  {
    const f4* xb4 = (const f4*)(x + (size_t)b * 32 * WD);
    f4* xw4 = (f4*)xw;
    for (int w = tid; w < WD / 4; w += NTHR) {
      f4 s = xb4[w];
#pragma unroll
      for (int h = 1; h < 32; ++h) s += xb4[h * (WD / 4) + w];
      xw4[w] = s;
    }
    f4* a4 = (f4*)acc;
    const f4 z = {0.f, 0.f, 0.f, 0.f};
    for (int i = tid; i < ACCN / 4; i += NTHR) a4[i] = z;
  }
  __syncthreads();

  const int lane = tid & 63;
  const int wv = tid >> 6;          // 0..7
  const int grp = lane >> 4;        // group 0..3 = chain slot in wave
  const int u = lane & 15;          // unit 0..15 (11..15 dummy)
  const int chain = wv * 4 + grp;   // 0..31
  const int d = chain & 3;          // direction
  const int ck = chain >> 2;        // chunk 0..7
  const bool fwd = ((d & 1) == 0);
  const int base = ck * CHUNK;
  const bool real = (u <= 10);
  const bool wr = real;
  const bool ck0z = (ck == 0);      // wrapped warm -> rezero at boundary
  // gate cols: i:0-10 f:11-21 o:33-43 a:44-54; dummy -> col 54, scl 0
  const int colI = real ? u : 54;
  const int colF = real ? (11 + u) : 54;
  const int colO = real ? (33 + u) : 54;
  const int colA = real ? (44 + u) : 54;
  const float sclS = real ? -LOG2E : 0.f;        // i, f, o
  const float sclA = real ? (-2.f * LOG2E) : 0.f;  // a

  const int p0 = fwd ? (base - WARM) : (WD - 1 - base + WARM);
  const int xd = fwd ? 1 : -1;
  const int ad = fwd ? ROW : -ROW;
  const int qd = fwd ? 3 : -3;

  auto loadU = [&](const float* U, int col, float scl, h2* Up) {
    float uv[12];
#pragma unroll
    for (int s = 0; s < NOUT; ++s) uv[s] = U[(d * NOUT + s) * 55 + col] * scl;
    uv[11] = 0.f;
#pragma unroll
    for (int k = 0; k < 6; ++k)
      Up[k] = __builtin_amdgcn_cvt_pkrtz(uv[2 * k], uv[2 * k + 1]);
  };

  // ---- Phase B: layer-1 scan ----
  {
    h2 UpI[6], UpF[6], UpO[6], UpA[6];
    loadU(U0, colI, sclS, UpI);
    loadU(U0, colF, sclS, UpF);
    loadU(U0, colO, sclS, UpO);
    loadU(U0, colA, sclA, UpA);
    const float WcI = W0[d * 55 + colI] * sclS;
    const float WcF = W0[d * 55 + colF] * sclS;
    const float WcO = W0[d * 55 + colO] * sclS;
    const float WcA = W0[d * 55 + colA] * sclA;
    const float bcI = b0[d * 55 + colI] * sclS;
    const float bcF = b0[d * 55 + colF] * sclS;
    const float bcO = b0[d * 55 + colO] * sclS;
    const float bcA = b0[d * 55 + colA] * sclA;

    int xo = p0;
    int ao = p0 * ROW + u;  // warm never writes; in-range from main loop on
    float hj = 0.f, cpr = 0.f;
    float gnI = 0.f, gnF = 0.f, gnO = 0.f, gnA = 0.f;
    const float xc = xw[xo & (WD - 1)];
    xo += xd;
    float giI = fmaf(xc, WcI, bcI);
    float giF = fmaf(xc, WcF, bcF);
    float giO = fmaf(xc, WcO, bcO);
    float giA = fmaf(xc, WcA, bcA);
    float xn = xw[xo & (WD - 1)];
    xo += xd;

#define PREP1                                                                  \
    const float xn2 = xw[xo & (WD - 1)]; /* prefetch t+2 (off-chain) */        \
    xo += xd;                                                                  \
    gnI = fmaf(xn, WcI, bcI);            /* input stage t+1 */                 \
    gnF = fmaf(xn, WcF, bcF);                                                  \
    gnO = fmaf(xn, WcO, bcO);                                                  \
    gnA = fmaf(xn, WcA, bcA);                                                  \
    xn = xn2;

    for (int t = 0; t < WARM; t += 2) {
      STEP(0, PREP1);
      giI = gnI; giF = gnF; giO = gnO; giA = gnA;
      STEP(0, PREP1);
      giI = gnI; giF = gnF; giO = gnO; giA = gnA;
    }
    // ck0's warm was wrapped garbage (uniform control flow); true initial
    // state is zero. gi pipeline holds REAL inputs for base, base+1.
    hj = ck0z ? 0.f : hj;
    cpr = ck0z ? 0.f : cpr;
    for (int t = 0; t < CHUNK; t += 2) {
      STEP(1, PREP1);
      giI = gnI; giF = gnF; giO = gnO; giA = gnA;
      STEP(1, PREP1);
      giI = gnI; giF = gnF; giO = gnO; giA = gnA;
    }
#undef PREP1
  }
  __syncthreads();

  // ---- Phase C: pack acc -> f16-pair ybf (+ zero pads); re-zero acc ----
  {
    const f2* a2 = (const f2*)acc;
    for (int i = tid; i < WD * YROW; i += NTHR) {
      const f2 v = a2[i];
      ybf[YPAD + i] = h2u(__builtin_amdgcn_cvt_pkrtz(v.x, v.y));
    }
    if (tid < YPAD) {
      ybf[tid] = 0;
      ybf[WD * YROW + YPAD + tid] = 0;
    }
  }
  __syncthreads();
  {
    f4* a4 = (f4*)acc;
    const f4 z = {0.f, 0.f, 0.f, 0.f};
    for (int i = tid; i < ACCN / 4; i += NTHR) a4[i] = z;
  }
  __syncthreads();

  // ---- Phase D: layer-2 scan ----
  {
    h2 UpI[6], UpF[6], UpO[6], UpA[6];
    h2 WpI[6], WpF[6], WpO[6], WpA[6];
    loadU(U1, colI, sclS, UpI);
    loadU(U1, colF, sclS, UpF);
    loadU(U1, colO, sclS, UpO);
    loadU(U1, colA, sclA, UpA);
    loadU(W1, colI, sclS, WpI);
    loadU(W1, colF, sclS, WpF);
    loadU(W1, colO, sclS, WpO);
    loadU(W1, colA, sclA, WpA);
    const float bcI = b1[d * 55 + colI] * sclS;
    const float bcF = b1[d * 55 + colF] * sclS;
    const float bcO = b1[d * 55 + colO] * sclS;
    const float bcA = b1[d * 55 + colA] * sclA;

    const u32x2* yv = (const u32x2*)ybf;  // row r -> yv[3r+6 .. 3r+8]
    int q = 3 * p0 + 6;  // ck0 warm reads OOB-in-LDS garbage (benign; state
                         // rezeroed at boundary -- proven pattern, R12)

    auto GIc = [&](const h2* Wp, float bc, u32x2 r0, u32x2 r1,
                   u32x2 r2) -> float {
      float A = dot2(u2h(r0.x), Wp[0], bc);
      A = dot2(u2h(r0.y), Wp[1], A);
      A = dot2(u2h(r1.x), Wp[2], A);
      A = dot2(u2h(r1.y), Wp[3], A);
      A = dot2(u2h(r2.x), Wp[4], A);
      A = dot2(u2h(r2.y), Wp[5], A);
      return A;
    };

    u32x2 c0 = yv[q];
    u32x2 c1 = yv[q + 1];
    u32x2 c2 = yv[q + 2];
    q += qd;
    u32x2 pr0 = yv[q];
    u32x2 pr1 = yv[q + 1];
    u32x2 pr2 = yv[q + 2];
    q += qd;

    float giI = GIc(WpI, bcI, c0, c1, c2);
    float giF = GIc(WpF, bcF, c0, c1, c2);
    float giO = GIc(WpO, bcO, c0, c1, c2);
    float giA = GIc(WpA, bcA, c0, c1, c2);

    int ao = p0 * ROW + u;
    float hj = 0.f, cpr = 0.f;
    float gnI = 0.f, gnF = 0.f, gnO = 0.f, gnA = 0.f;

#define PREP2                                                                  \
    const u32x2 n0 = yv[q];          /* prefetch row t+2 (off-chain) */        \
    const u32x2 n1 = yv[q + 1];                                                \
    const u32x2 n2 = yv[q + 2];                                                \
    q += qd;                                                                   \
    gnI = GIc(WpI, bcI, pr0, pr1, pr2); /* input stage t+1 */                  \
    gnF = GIc(WpF, bcF, pr0, pr1, pr2);                                        \
    gnO = GIc(WpO, bcO, pr0, pr1, pr2);                                        \
    gnA = GIc(WpA, bcA, pr0, pr1, pr2);                                        \
    pr0 = n0;                                                                  \
    pr1 = n1;                                                                  \
    pr2 = n2;

    for (int t = 0; t < WARM; t += 2) {
      STEP(0, PREP2);
      giI = gnI; giF = gnF; giO = gnO; giA = gnA;
      STEP(0, PREP2);
      giI = gnI; giF = gnF; giO = gnO; giA = gnA;
    }
    hj = ck0z ? 0.f : hj;
    cpr = ck0z ? 0.f : cpr;
    for (int t = 0; t < CHUNK; t += 2) {
      STEP(1, PREP2);
      giI = gnI; giF = gnF; giO = gnO; giA = gnA;
      STEP(1, PREP2);
      giI = gnI; giF = gnF; giO = gnO; giA = gnA;
    }
#undef PREP2
  }
  __syncthreads();

  // ---- Phase E: writeout out[b][j][w] = acc[w*ROW+j] ----
  float* ob = out + (size_t)b * (NOUT * WD);
  for (int i = tid; i < NOUT * WD; i += NTHR) {
    const int jj = i >> 11;
    const int w = i & (WD - 1);
    ob[i] = acc[w * ROW + jj];
  }
}

extern "C" void kernel_launch(void* const* d_in, const int* in_sizes, int n_in,
                              void* d_out, int out_size, void* d_ws,
                              size_t ws_size, hipStream_t stream) {
  const float* x  = (const float*)d_in[0];
  const float* W0 = (const float*)d_in[1];
  const float* U0 = (const float*)d_in[2];
  const float* b0 = (const float*)d_in[3];
  const float* W1 = (const float*)d_in[4];
  const float* U1 = (const float*)d_in[5];
  const float* b1 = (const float*)d_in[6];
  float* out = (float*)d_out;

  mdlstm_fused<<<NB, NTHR, 0, stream>>>(x, W0, U0, b0, W1, U1, b1, out);
}

// Round 7
// 386.442 us; speedup vs baseline: 1.4367x; 1.2354x over previous
//
#include <hip/hip_runtime.h>
#include <hip/hip_bf16.h>

// 2-layer 4-direction MDLSTM, fused, one dispatch. B=256, Wd=2048, OUT=11.
// R14: R13's unit-per-lane 4-chains-per-wave layout, with the h-distribution
// moved OFF the DS pipe onto pure VALU. R12/R13 showed DS crossbar ops
// (bpermute/swizzle) on the serial chain cost ~+900 cyc/step unhidden at
// 2-4 waves/SIMD; R13's per-chain VALU issue (81 cyc) was excellent.
// Distribution = rotate-reduce: 2 quad_perm + cvt_pkrtz put pair floor(u/2)
// in EVERY lane; 7x dpp row_ror:2 rotate pairs through the 16-lane group;
// each lane folds dot2 against U-registers pre-permuted at setup (8 slots,
// pairs 6/7 zero => exact). Rotation direction resolved by a runtime probe
// (dpp on lane id) so ror semantics can't silently break correctness.
// 512 thr = 8 waves = 32 chains = 4 dirs x 8 chunks (CHUNK 256), uniform
// WARM=64 (ck0 wrapped garbage warm + state rezero; proven R12/R13).
// f32 LDS atomic acc (proven); f16-pair y strip; exp2-folded activations.

#define NOUT 11
#define WD 2048
#define NB 256
#define ROW 12
#define ACCN (WD * ROW)
#define YROW 6
#define YPAD 12
#define YBFN (WD * YROW + 2 * YPAD)

#define NTHR 512
#define NCK 8       // chunks per direction
#define CHUNK 256   // WD / NCK
#define WARM 64     // uniform warm (ck0 wrapped+rezeroed); even

typedef float f2 __attribute__((ext_vector_type(2)));
typedef float f4 __attribute__((ext_vector_type(4)));
typedef unsigned int u32;
typedef u32 u32x2 __attribute__((ext_vector_type(2)));
typedef __fp16 h2 __attribute__((ext_vector_type(2)));

#define LOG2E 1.4426950408889634f

union UH { u32 u; h2 h; };
__device__ __forceinline__ u32 h2u(h2 v) { UH x; x.h = v; return x.u; }
__device__ __forceinline__ h2 u2h(u32 v) { UH x; x.u = v; return x.h; }

template <int CTRL>
__device__ __forceinline__ float dppf(float v) {
  return __int_as_float(__builtin_amdgcn_update_dpp(
      __float_as_int(v), __float_as_int(v), CTRL, 0xF, 0xF, false));
}
// row_ror:2 on a packed h2 (u32 bits); wraps within 16-lane rows.
__device__ __forceinline__ h2 rorh(h2 v) {
  return u2h((u32)__builtin_amdgcn_update_dpp(
      (int)h2u(v), (int)h2u(v), 0x122, 0xF, 0xF, false));
}
__device__ __forceinline__ float rcp_(float x) { return __builtin_amdgcn_rcpf(x); }
__device__ __forceinline__ float exp2_(float x) { return __builtin_amdgcn_exp2f(x); }
__device__ __forceinline__ float dot2(h2 a, h2 b, float c) {
  return __builtin_amdgcn_fdot2(a, b, c, false);
}

// DOACC: compile-time 0/1 (warm-up steps don't accumulate).
// In scope: hj, cpr, giI/F/O/A, ao, ad, UpI/F/O/A[8], wr, acc.
// __VA_ARGS__ = off-chain PREP (sets gnI/F/O/A).
#define STEP(DOACC, ...)                                                       \
  do {                                                                         \
    const float hEv = dppf<0xA0>(hj); /* quad_perm[0,0,2,2]: h_{2*(u>>1)} */   \
    const float hOd = dppf<0xF5>(hj); /* quad_perm[1,1,3,3]: h_{2*(u>>1)+1} */ \
    h2 rv = __builtin_amdgcn_cvt_pkrtz(hEv, hOd); /* pair p0 in every lane */  \
    __VA_ARGS__                                                                \
    float gI = dot2(rv, UpI[0], giI);                                          \
    float gF = dot2(rv, UpF[0], giF);                                          \
    float gO = dot2(rv, UpO[0], giO);                                          \
    float gA = dot2(rv, UpA[0], giA);                                          \
    _Pragma("unroll")                                                          \
    for (int s = 1; s < 8; ++s) {                                              \
      rv = rorh(rv);                                                           \
      gI = dot2(rv, UpI[s], gI);                                               \
      gF = dot2(rv, UpF[s], gF);                                               \
      gO = dot2(rv, UpO[s], gO);                                               \
      gA = dot2(rv, UpA[s], gA);                                               \
    }                                                                          \
    const float sI = rcp_(1.0f + exp2_(gI));                                   \
    const float sF = rcp_(1.0f + exp2_(gF));                                   \
    const float sO = rcp_(1.0f + exp2_(gO));                                   \
    const float sA = rcp_(1.0f + exp2_(gA));                                   \
    const float taS = fmaf(-4.0f * LOG2E, sA, 2.0f * LOG2E); /* -2L*tanh */    \
    cpr = fmaf(sF, cpr, sI * taS); /* cpr == -2*log2e*c */                     \
    const float r2t = rcp_(1.0f + exp2_(cpr)); /* sigma(2c) */                 \
    const float sO2 = sO + sO;                                                 \
    hj = fmaf(sO2, r2t, -sO); /* o * tanh(c) */                                \
    if (DOACC && wr) atomicAdd(&acc[ao], hj);                                  \
    ao += ad;                                                                  \
  } while (0)

__global__ __launch_bounds__(NTHR, 1) void mdlstm_fused(
    const float* __restrict__ x, const float* __restrict__ W0,
    const float* __restrict__ U0, const float* __restrict__ b0,
    const float* __restrict__ W1, const float* __restrict__ U1,
    const float* __restrict__ b1, float* __restrict__ out) {
  __shared__ __align__(16) float acc[ACCN];  // 96 KB
  __shared__ __align__(16) u32 ybf[YBFN];    // 48.1 KB (xw f32 | y f16-pairs)

  const int tid = threadIdx.x;
  const int b = blockIdx.x;
  float* xw = (float*)ybf;

  // ---- Phase A: height-sum x -> xw; zero acc ----
  {
    const f4* xb4 = (const f4*)(x + (size_t)b * 32 * WD);
    f4* xw4 = (f4*)xw;
    for (int w = tid; w < WD / 4; w += NTHR) {
      f4 s = xb4[w];
#pragma unroll
      for (int h = 1; h < 32; ++h) s += xb4[h * (WD / 4) + w];
      xw4[w] = s;
    }
    f4* a4 = (f4*)acc;
    const f4 z = {0.f, 0.f, 0.f, 0.f};
    for (int i = tid; i < ACCN / 4; i += NTHR) a4[i] = z;
  }
  __syncthreads();

  const int lane = tid & 63;
  const int wv = tid >> 6;          // 0..7
  const int grp = lane >> 4;        // group 0..3 = chain slot in wave
  const int u = lane & 15;          // unit 0..15 (11..15 dummy)
  const int chain = wv * 4 + grp;   // 0..31
  const int d = chain & 3;          // direction
  const int ck = chain >> 2;        // chunk 0..7
  const bool fwd = ((d & 1) == 0);
  const int base = ck * CHUNK;
  const bool real = (u <= 10);
  const bool wr = real;
  const bool ck0z = (ck == 0);      // wrapped warm -> rezero at boundary
  // gate cols: i:0-10 f:11-21 o:33-43 a:44-54; dummy -> col 54, scl 0
  const int colI = real ? u : 54;
  const int colF = real ? (11 + u) : 54;
  const int colO = real ? (33 + u) : 54;
  const int colA = real ? (44 + u) : 54;
  const float sclS = real ? -LOG2E : 0.f;          // i, f, o
  const float sclA = real ? (-2.f * LOG2E) : 0.f;  // a

  // Rotation-direction probe: does row_ror:2 read lane i+2 or i-2?
  const int li = lane & 15;
  const int pv =
      __builtin_amdgcn_update_dpp(0, li, 0x122, 0xF, 0xF, false);
  const bool rplus = (pv == ((li + 2) & 15));
  const int p0 = li >> 1;  // own pair index 0..7

  const int p0pos = fwd ? (base - WARM) : (WD - 1 - base + WARM);
  const int xd = fwd ? 1 : -1;
  const int ad = fwd ? ROW : -ROW;
  const int qd = fwd ? 3 : -3;

  // Rotated U slots: slot s must hold the U columns of the pair that
  // arrives in rv after s rotations = pair (p0 +/- s) & 7.
  auto loadUrot = [&](const float* U, int col, float scl, h2* Up) {
#pragma unroll
    for (int s = 0; s < 8; ++s) {
      const int pr = rplus ? ((p0 + s) & 7) : ((p0 + 8 - s) & 7);
      const int r0 = 2 * pr, r1 = r0 + 1;
      const int rr0 = (r0 <= 10) ? r0 : 0;
      const int rr1 = (r1 <= 10) ? r1 : 0;
      float a = U[(d * NOUT + rr0) * 55 + col] * scl;
      float bb = U[(d * NOUT + rr1) * 55 + col] * scl;
      a = (r0 <= 10) ? a : 0.f;
      bb = (r1 <= 10) ? bb : 0.f;
      Up[s] = __builtin_amdgcn_cvt_pkrtz(a, bb);
    }
  };
  // Plain 6-pair form (for the y-side dots; no rotation there).
  auto loadW = [&](const float* U, int col, float scl, h2* Up) {
    float uv[12];
#pragma unroll
    for (int s = 0; s < NOUT; ++s) uv[s] = U[(d * NOUT + s) * 55 + col] * scl;
    uv[11] = 0.f;
#pragma unroll
    for (int k = 0; k < 6; ++k)
      Up[k] = __builtin_amdgcn_cvt_pkrtz(uv[2 * k], uv[2 * k + 1]);
  };

  // ---- Phase B: layer-1 scan ----
  {
    h2 UpI[8], UpF[8], UpO[8], UpA[8];
    loadUrot(U0, colI, sclS, UpI);
    loadUrot(U0, colF, sclS, UpF);
    loadUrot(U0, colO, sclS, UpO);
    loadUrot(U0, colA, sclA, UpA);
    const float WcI = W0[d * 55 + colI] * sclS;
    const float WcF = W0[d * 55 + colF] * sclS;
    const float WcO = W0[d * 55 + colO] * sclS;
    const float WcA = W0[d * 55 + colA] * sclA;
    const float bcI = b0[d * 55 + colI] * sclS;
    const float bcF = b0[d * 55 + colF] * sclS;
    const float bcO = b0[d * 55 + colO] * sclS;
    const float bcA = b0[d * 55 + colA] * sclA;

    int xo = p0pos;
    int ao = p0pos * ROW + u;  // warm never writes; in-range from main loop
    float hj = 0.f, cpr = 0.f;
    float gnI = 0.f, gnF = 0.f, gnO = 0.f, gnA = 0.f;
    const float xc = xw[xo & (WD - 1)];
    xo += xd;
    float giI = fmaf(xc, WcI, bcI);
    float giF = fmaf(xc, WcF, bcF);
    float giO = fmaf(xc, WcO, bcO);
    float giA = fmaf(xc, WcA, bcA);
    float xn = xw[xo & (WD - 1)];
    xo += xd;

#define PREP1                                                                  \
    const float xn2 = xw[xo & (WD - 1)]; /* prefetch t+2 (off-chain) */        \
    xo += xd;                                                                  \
    gnI = fmaf(xn, WcI, bcI);            /* input stage t+1 */                 \
    gnF = fmaf(xn, WcF, bcF);                                                  \
    gnO = fmaf(xn, WcO, bcO);                                                  \
    gnA = fmaf(xn, WcA, bcA);                                                  \
    xn = xn2;

    for (int t = 0; t < WARM; t += 2) {
      STEP(0, PREP1);
      giI = gnI; giF = gnF; giO = gnO; giA = gnA;
      STEP(0, PREP1);
      giI = gnI; giF = gnF; giO = gnO; giA = gnA;
    }
    // ck0's warm was wrapped garbage (uniform control flow); true initial
    // state is zero. gi pipeline holds REAL inputs for base, base+1.
    hj = ck0z ? 0.f : hj;
    cpr = ck0z ? 0.f : cpr;
    for (int t = 0; t < CHUNK; t += 2) {
      STEP(1, PREP1);
      giI = gnI; giF = gnF; giO = gnO; giA = gnA;
      STEP(1, PREP1);
      giI = gnI; giF = gnF; giO = gnO; giA = gnA;
    }
#undef PREP1
  }
  __syncthreads();

  // ---- Phase C: pack acc -> f16-pair ybf (+ zero pads); re-zero acc ----
  {
    const f2* a2 = (const f2*)acc;
    for (int i = tid; i < WD * YROW; i += NTHR) {
      const f2 v = a2[i];
      ybf[YPAD + i] = h2u(__builtin_amdgcn_cvt_pkrtz(v.x, v.y));
    }
    if (tid < YPAD) {
      ybf[tid] = 0;
      ybf[WD * YROW + YPAD + tid] = 0;
    }
  }
  __syncthreads();
  {
    f4* a4 = (f4*)acc;
    const f4 z = {0.f, 0.f, 0.f, 0.f};
    for (int i = tid; i < ACCN / 4; i += NTHR) a4[i] = z;
  }
  __syncthreads();

  // ---- Phase D: layer-2 scan ----
  {
    h2 UpI[8], UpF[8], UpO[8], UpA[8];
    h2 WpI[6], WpF[6], WpO[6], WpA[6];
    loadUrot(U1, colI, sclS, UpI);
    loadUrot(U1, colF, sclS, UpF);
    loadUrot(U1, colO, sclS, UpO);
    loadUrot(U1, colA, sclA, UpA);
    loadW(W1, colI, sclS, WpI);
    loadW(W1, colF, sclS, WpF);
    loadW(W1, colO, sclS, WpO);
    loadW(W1, colA, sclA, WpA);
    const float bcI = b1[d * 55 + colI] * sclS;
    const float bcF = b1[d * 55 + colF] * sclS;
    const float bcO = b1[d * 55 + colO] * sclS;
    const float bcA = b1[d * 55 + colA] * sclA;

    const u32x2* yv = (const u32x2*)ybf;  // row r -> yv[3r+6 .. 3r+8]
    int q = 3 * p0pos + 6;  // ck0 warm reads in-LDS garbage (benign; state
                            // rezeroed at boundary -- proven pattern)

    auto GIc = [&](const h2* Wp, float bc, u32x2 r0, u32x2 r1,
                   u32x2 r2) -> float {
      float A = dot2(u2h(r0.x), Wp[0], bc);
      A = dot2(u2h(r0.y), Wp[1], A);
      A = dot2(u2h(r1.x), Wp[2], A);
      A = dot2(u2h(r1.y), Wp[3], A);
      A = dot2(u2h(r2.x), Wp[4], A);
      A = dot2(u2h(r2.y), Wp[5], A);
      return A;
    };

    u32x2 c0 = yv[q];
    u32x2 c1 = yv[q + 1];
    u32x2 c2 = yv[q + 2];
    q += qd;
    u32x2 pr0 = yv[q];
    u32x2 pr1 = yv[q + 1];
    u32x2 pr2 = yv[q + 2];
    q += qd;

    float giI = GIc(WpI, bcI, c0, c1, c2);
    float giF = GIc(WpF, bcF, c0, c1, c2);
    float giO = GIc(WpO, bcO, c0, c1, c2);
    float giA = GIc(WpA, bcA, c0, c1, c2);

    int ao = p0pos * ROW + u;
    float hj = 0.f, cpr = 0.f;
    float gnI = 0.f, gnF = 0.f, gnO = 0.f, gnA = 0.f;

#define PREP2                                                                  \
    const u32x2 n0 = yv[q];          /* prefetch row t+2 (off-chain) */        \
    const u32x2 n1 = yv[q + 1];                                                \
    const u32x2 n2 = yv[q + 2];                                                \
    q += qd;                                                                   \
    gnI = GIc(WpI, bcI, pr0, pr1, pr2); /* input stage t+1 */                  \
    gnF = GIc(WpF, bcF, pr0, pr1, pr2);                                        \
    gnO = GIc(WpO, bcO, pr0, pr1, pr2);                                        \
    gnA = GIc(WpA, bcA, pr0, pr1, pr2);                                        \
    pr0 = n0;                                                                  \
    pr1 = n1;                                                                  \
    pr2 = n2;

    for (int t = 0; t < WARM; t += 2) {
      STEP(0, PREP2);
      giI = gnI; giF = gnF; giO = gnO; giA = gnA;
      STEP(0, PREP2);
      giI = gnI; giF = gnF; giO = gnO; giA = gnA;
    }
    hj = ck0z ? 0.f : hj;
    cpr = ck0z ? 0.f : cpr;
    for (int t = 0; t < CHUNK; t += 2) {
      STEP(1, PREP2);
      giI = gnI; giF = gnF; giO = gnO; giA = gnA;
      STEP(1, PREP2);
      giI = gnI; giF = gnF; giO = gnO; giA = gnA;
    }
#undef PREP2
  }
  __syncthreads();

  // ---- Phase E: writeout out[b][j][w] = acc[w*ROW+j] ----
  float* ob = out + (size_t)b * (NOUT * WD);
  for (int i = tid; i < NOUT * WD; i += NTHR) {
    const int jj = i >> 11;
    const int w = i & (WD - 1);
    ob[i] = acc[w * ROW + jj];
  }
}

extern "C" void kernel_launch(void* const* d_in, const int* in_sizes, int n_in,
                              void* d_out, int out_size, void* d_ws,
                              size_t ws_size, hipStream_t stream) {
  const float* x  = (const float*)d_in[0];
  const float* W0 = (const float*)d_in[1];
  const float* U0 = (const float*)d_in[2];
  const float* b0 = (const float*)d_in[3];
  const float* W1 = (const float*)d_in[4];
  const float* U1 = (const float*)d_in[5];
  const float* b1 = (const float*)d_in[6];
  float* out = (float*)d_out;

  mdlstm_fused<<<NB, NTHR, 0, stream>>>(x, W0, U0, b0, W1, U1, b1, out);
}